// Round 5
// baseline (691.178 us; speedup 1.0000x reference)
//
#include <hip/hip_runtime.h>
#include <hip/hip_bf16.h>

// InterestEvolve: attention-modulated GRU scan. B=2048, T=200, D=128, U=128.
//
// R13: producer/consumer wave specialization.
//  - Waves 0-3: CONSUMERS, 32 gatecols each (R10's verified tile code, x from
//    LDS). Halves the duplicated per-step LDS fragment reads vs R8 (48 vs 96
//    b128/step/CU): every wave reads identical h/rh/x fragments, so fewer,
//    wider waves cut redundant LDS traffic (R8's top cost, ~1150 cy/step).
//  - Waves 4-7: PRODUCERS, double-buffer-stage x (fp32->bf16 pack) and Att
//    for chunk ch+1 while consumers scan chunk ch. Removes R8's 17 exposed
//    synchronous staging phases AND gives each SIMD a 2nd resident wave
//    (latency hiding that R9's 1-wave/SIMD lacked).
//  - Both branches execute an IDENTICAL barrier skeleton: 2 block_sync_lds
//    per step, nothing else. Prologue stages chunk 0 with all 512 threads.
//  - block_sync_lds waits lgkmcnt only (producers' global loads stay in
//    flight across barriers), sched_barrier(0)-hardened (rule #18).
//  - Weights (192 VGPR) live only in the consumer branch; producer px bursts
//    live only in the producer branch -> allocator takes max, not sum.
// 128 blocks x 512 threads, launch_bounds(512,2).

#define T_LEN 200
#define D_DIM 128
#define U_DIM 128
#define BM    16
#define CH    12
#define NCH   ((T_LEN + CH - 1) / CH)   // 17, last chunk L=8
#define KCS   136          // ushorts per kchunk slot-row: 16 batch*8 + 8 pad
#define XSTEP (16 * KCS)   // ushorts per staged step (2176)

typedef __attribute__((ext_vector_type(8))) short bf16x8;
typedef __attribute__((ext_vector_type(4))) float f32x4;
typedef __attribute__((ext_vector_type(4))) unsigned int uint4v;

#define MFMA __builtin_amdgcn_mfma_f32_16x16x32_bf16

static __device__ __forceinline__ unsigned short f2bf(float f) {
    unsigned int u = __builtin_bit_cast(unsigned int, f);
    u += 0x7fffu + ((u >> 16) & 1u);       // round-to-nearest-even
    return (unsigned short)(u >> 16);
}
static __device__ __forceinline__ unsigned int pkbf2(float a, float b) {
    float2 t; t.x = a; t.y = b;
    __hip_bfloat162 v = __float22bfloat162_rn(t);   // v_cvt_pk_bf16_f32
    unsigned int u; __builtin_memcpy(&u, &v, 4);
    return u;
}
static __device__ __forceinline__ uint4v pack8u(float4 lo, float4 hi) {
    uint4v v;
    v[0] = pkbf2(lo.x, lo.y); v[1] = pkbf2(lo.z, lo.w);
    v[2] = pkbf2(hi.x, hi.y); v[3] = pkbf2(hi.z, hi.w);
    return v;
}
static __device__ __forceinline__ float fast_exp2(float x) {
#if __has_builtin(__builtin_amdgcn_exp2f)
    return __builtin_amdgcn_exp2f(x);
#else
    return exp2f(x);
#endif
}
static __device__ __forceinline__ float fast_rcp(float x) {
#if __has_builtin(__builtin_amdgcn_rcpf)
    return __builtin_amdgcn_rcpf(x);
#else
    return 1.0f / x;
#endif
}
// Barrier waiting ONLY on LDS ops; producers' global loads stay in flight.
// sched_barrier(0) on both sides pins ds ops across it (rule #18).
static __device__ __forceinline__ void block_sync_lds() {
    asm volatile("s_waitcnt lgkmcnt(0)" ::: "memory");
    __builtin_amdgcn_sched_barrier(0);
    __builtin_amdgcn_s_barrier();
    __builtin_amdgcn_sched_barrier(0);
}

// consumer: x-part accumulators (3 gates x 2 tiles) from an LDS step slot
#define XPART(SRC) do {                                                        \
    bf16x8 xf_[4];                                                             \
    _Pragma("unroll")                                                          \
    for (int kt = 0; kt < 4; ++kt)                                             \
        xf_[kt] = *(const bf16x8*)&(SRC)[(4 * kt + q) * KCS + ln * 8];         \
    _Pragma("unroll")                                                          \
    for (int tl = 0; tl < 2; ++tl) {                                           \
        acc_r[tl] = nbr[tl]; acc_u[tl] = nbu[tl]; acc_h[tl] = bh2[tl];         \
        _Pragma("unroll")                                                      \
        for (int kt = 0; kt < 4; ++kt) {                                       \
            acc_r[tl] = MFMA(wr[tl][kt + 4], xf_[kt], acc_r[tl], 0, 0, 0);     \
            acc_u[tl] = MFMA(wu[tl][kt + 4], xf_[kt], acc_u[tl], 0, 0, 0);     \
            acc_h[tl] = MFMA(wh[tl][kt],     xf_[kt], acc_h[tl], 0, 0, 0);     \
        }                                                                      \
    }                                                                          \
} while (0)

// producer: issue 4 step-slots of global loads / pack+write them
#define P_ISSUE(PX, SB) do {                                                   \
    _Pragma("unroll")                                                          \
    for (int k = 0; k < 4; ++k) {                                              \
        int t_ = tn0 + (SB) + k; t_ = (t_ < T_LEN) ? t_ : (T_LEN - 1);         \
        const float* src_ = xb + (size_t)t_ * D_DIM;                           \
        (PX)[2 * k]     = *(const float4*)(src_);                              \
        (PX)[2 * k + 1] = *(const float4*)(src_ + 4);                          \
    }                                                                          \
} while (0)
#define P_WRITE(PX, SB) do {                                                   \
    _Pragma("unroll")                                                          \
    for (int k = 0; k < 4; ++k)                                                \
        *(uint4v*)&dst[((SB) + k) * XSTEP + cs * KCS + srow * 8] =             \
            pack8u((PX)[2 * k], (PX)[2 * k + 1]);                              \
} while (0)

__global__ __launch_bounds__(512, 2)
void gru_scan_kernel(const float* __restrict__ X,    // (B,T,D)
                     const float* __restrict__ Att,  // (B,T,1)
                     const float* __restrict__ Wu, const float* __restrict__ bu,
                     const float* __restrict__ Wr, const float* __restrict__ br,
                     const float* __restrict__ Wh, const float* __restrict__ bh,
                     float* __restrict__ out)        // (B,U)
{
    __shared__ __align__(16) unsigned short x_sm[2][CH * XSTEP];  // 104448 B
    __shared__ __align__(16) unsigned short h_bf[XSTEP];          // 4352 B
    __shared__ __align__(16) unsigned short rh_bf[XSTEP];         // 4352 B
    __shared__ float a_sm[2][CH * BM];                            // 1536 B

    const int tid  = threadIdx.x;
    const int wave = tid >> 6;
    const int lane = tid & 63;
    const int q    = lane >> 4;
    const int ln   = lane & 15;
    const int b0   = blockIdx.x * BM;

    const float INVLN2 = 1.4426950408889634f;

    // ---- zero h/rh exchange buffers (full padded size) ----
    {
        unsigned int* hz = (unsigned int*)h_bf;
        unsigned int* rz = (unsigned int*)rh_bf;
        for (int i = tid; i < XSTEP / 2; i += 512) { hz[i] = 0; rz[i] = 0; }
    }

    // ---- prologue: stage chunk 0 with all 512 threads (R8 map) ----
    {
        const int s2   = tid >> 8;
        const int srow = (tid >> 4) & 15;
        const int cs   = tid & 15;
        const float* xb = X + (size_t)(b0 + srow) * T_LEN * D_DIM + cs * 8;
        float4 px[CH];
        #pragma unroll
        for (int w2 = 0; w2 < CH / 2; ++w2) {
            const int t = 2 * w2 + s2;                    // 0..11 < T_LEN
            const float* src = xb + (size_t)t * D_DIM;
            px[2 * w2]     = *(const float4*)(src);
            px[2 * w2 + 1] = *(const float4*)(src + 4);
        }
        float a_px = 0.0f;
        if (tid < BM * CH) a_px = Att[(size_t)(b0 + (tid & 15)) * T_LEN + (tid >> 4)];
        #pragma unroll
        for (int w2 = 0; w2 < CH / 2; ++w2) {
            const int s = 2 * w2 + s2;
            *(uint4v*)&x_sm[0][s * XSTEP + cs * KCS + srow * 8] =
                pack8u(px[2 * w2], px[2 * w2 + 1]);
        }
        if (tid < BM * CH) a_sm[0][tid] = a_px;
    }
    __syncthreads();

    if (wave < 4) {
        // ================= CONSUMER: 32 gatecols per wave =================
        bf16x8 wu[2][8], wr[2][8], wh[2][8];            // 192 VGPR
        f32x4 nbu[2], nbr[2], bh2[2];
        #pragma unroll
        for (int tl = 0; tl < 2; ++tl) {
            const int tb = 32 * wave + 16 * tl;
            const int c  = tb + ln;
            const f32x4 bu4 = *(const f32x4*)&bu[tb + 4 * q];
            const f32x4 br4 = *(const f32x4*)&br[tb + 4 * q];
            const f32x4 bh4 = *(const f32x4*)&bh[tb + 4 * q];
            #pragma unroll
            for (int r = 0; r < 4; ++r) {
                nbu[tl][r] = -bu4[r] * INVLN2;
                nbr[tl][r] = -br4[r] * INVLN2;
                bh2[tl][r] = 2.0f * bh4[r] * INVLN2;
            }
            #pragma unroll
            for (int kt = 0; kt < 8; ++kt) {
                const int k0 = 32 * kt + 8 * q;
                bf16x8 vu, vr, vh;
                #pragma unroll
                for (int j = 0; j < 8; ++j) {
                    vu[j] = (short)f2bf(Wu[(k0 + j) * U_DIM + c] * -INVLN2);
                    vr[j] = (short)f2bf(Wr[(k0 + j) * U_DIM + c] * -INVLN2);
                    vh[j] = (short)f2bf(Wh[(k0 + j) * U_DIM + c] * (2.0f * INVLN2));
                }
                wu[tl][kt] = vu; wr[tl][kt] = vr; wh[tl][kt] = vh;
            }
        }

        float hreg[2][4] = {{0.f,0.f,0.f,0.f},{0.f,0.f,0.f,0.f}};
        const int c8base = (4 * wave) * KCS + ln * 8 + (q & 1) * 4;
        const int c8q    = (q >> 1) * KCS;

        f32x4 acc_r[2], acc_u[2], acc_h[2];
        XPART(&x_sm[0][0]);                 // x-part for t=0

        int t0 = 0;
        for (int ch = 0; ch < NCH; ++ch) {
            const int L = (t0 + CH <= T_LEN) ? CH : (T_LEN - t0);
            const unsigned short* xcur = &x_sm[ch & 1][0];
            const float* ab = &a_sm[ch & 1][0];

            for (int s = 0; s < L; ++s) {
                // -------- region 1: h-parts (r critical, 2+2 split) --------
                bf16x8 hf[4];
                #pragma unroll
                for (int kt = 0; kt < 4; ++kt)
                    hf[kt] = *(const bf16x8*)&h_bf[(4 * kt + q) * KCS + ln * 8];
                const float a_att = ab[s * BM + ln];

                f32x4 ra[2], rb[2];
                #pragma unroll
                for (int tl = 0; tl < 2; ++tl) {
                    ra[tl] = acc_r[tl]; rb[tl] = (f32x4)0.0f;
                    ra[tl] = MFMA(wr[tl][0], hf[0], ra[tl], 0, 0, 0);
                    rb[tl] = MFMA(wr[tl][2], hf[2], rb[tl], 0, 0, 0);
                    ra[tl] = MFMA(wr[tl][1], hf[1], ra[tl], 0, 0, 0);
                    rb[tl] = MFMA(wr[tl][3], hf[3], rb[tl], 0, 0, 0);
                    #pragma unroll
                    for (int kt = 0; kt < 4; ++kt)
                        acc_u[tl] = MFMA(wu[tl][kt], hf[kt], acc_u[tl], 0, 0, 0);
                }
                #pragma unroll
                for (int tl = 0; tl < 2; ++tl) {
                    float rh[4];
                    #pragma unroll
                    for (int r = 0; r < 4; ++r) {
                        float zr = ra[tl][r] + rb[tl][r];           // = -z_r/ln2
                        float rv = fast_rcp(1.0f + fast_exp2(zr));  // sigmoid
                        rh[r] = rv * hreg[tl][r];
                    }
                    uint2 wv; wv.x = pkbf2(rh[0], rh[1]); wv.y = pkbf2(rh[2], rh[3]);
                    *(uint2*)&rh_bf[c8base + c8q + 2 * tl * KCS] = wv;
                }
                block_sync_lds();   // rh handoff

                // -------- region 2 --------
                bf16x8 rf[4];
                #pragma unroll
                for (int kt = 0; kt < 4; ++kt)
                    rf[kt] = *(const bf16x8*)&rh_bf[(4 * kt + q) * KCS + ln * 8];

                float uq[2][4];
                #pragma unroll
                for (int tl = 0; tl < 2; ++tl)
                    #pragma unroll
                    for (int r = 0; r < 4; ++r)
                        uq[tl][r] = fast_rcp(1.0f + fast_exp2(acc_u[tl][r])) * a_att;

                #pragma unroll
                for (int tl = 0; tl < 2; ++tl) {
                    f32x4 ha = acc_h[tl], hb = (f32x4)0.0f;
                    ha = MFMA(wh[tl][4], rf[0], ha, 0, 0, 0);
                    hb = MFMA(wh[tl][6], rf[2], hb, 0, 0, 0);
                    ha = MFMA(wh[tl][5], rf[1], ha, 0, 0, 0);
                    hb = MFMA(wh[tl][7], rf[3], hb, 0, 0, 0);
                    #pragma unroll
                    for (int r = 0; r < 4; ++r) {
                        float z  = ha[r] + hb[r];                                // 2*z_h/ln2
                        float hh = 1.0f - 2.0f * fast_rcp(1.0f + fast_exp2(z));  // tanh
                        float ho = hreg[tl][r];
                        hreg[tl][r] = ho + uq[tl][r] * (hh - ho);
                    }
                    uint2 wv; wv.x = pkbf2(hreg[tl][0], hreg[tl][1]);
                    wv.y = pkbf2(hreg[tl][2], hreg[tl][3]);
                    *(uint2*)&h_bf[c8base + c8q + 2 * tl * KCS] = wv;
                }

                // x-part accumulators for the next step (off critical path)
                if (s + 1 < L) {
                    XPART(xcur + (s + 1) * XSTEP);
                } else if (ch + 1 < NCH) {
                    XPART(&x_sm[(ch + 1) & 1][0]);     // staged by producers
                }
                block_sync_lds();   // h handoff
            }
            t0 += CH;
        }

        // ---- store h_final ----
        #pragma unroll
        for (int tl = 0; tl < 2; ++tl) {
            f32x4 v;
            #pragma unroll
            for (int r = 0; r < 4; ++r) v[r] = hreg[tl][r];
            *(f32x4*)&out[(size_t)(b0 + ln) * U_DIM + 32 * wave + 16 * tl + 4 * q] = v;
        }
    } else {
        // ================= PRODUCER: stage chunk ch+1 =================
        const int tid2 = tid & 255;
        const int srow = (tid2 >> 4) & 15;
        const int cs   = tid2 & 15;
        const float* xb = X + (size_t)(b0 + srow) * T_LEN * D_DIM + cs * 8;

        int t0 = 0;
        for (int ch = 0; ch < NCH; ++ch) {
            const int L = (t0 + CH <= T_LEN) ? CH : (T_LEN - t0);
            const bool st = (ch + 1 < NCH);
            const int tn0 = t0 + CH;
            unsigned short* dst = &x_sm[(ch + 1) & 1][0];
            float4 pxA[8], pxB[8], pxC[8];
            float av = 0.0f;

            for (int s = 0; s < L; ++s) {
                // region-1 slot
                if (st && s == 0) {
                    P_ISSUE(pxA, 0);
                    if (tid2 < BM * CH) {
                        int ta = tn0 + (tid2 >> 4);
                        ta = (ta < T_LEN) ? ta : (T_LEN - 1);
                        av = Att[(size_t)(b0 + (tid2 & 15)) * T_LEN + ta];
                    }
                }
                block_sync_lds();
                // region-2 slot
                if (st) {
                    if (s == 1) {
                        P_WRITE(pxA, 0);
                        P_ISSUE(pxB, 4);
                        if (tid2 < BM * CH) a_sm[(ch + 1) & 1][tid2] = av;
                    } else if (s == 2) {
                        P_WRITE(pxB, 4);
                        P_ISSUE(pxC, 8);
                    } else if (s == 3) {
                        P_WRITE(pxC, 8);
                    }
                }
                block_sync_lds();
            }
            t0 += CH;
        }
    }
}

extern "C" void kernel_launch(void* const* d_in, const int* in_sizes, int n_in,
                              void* d_out, int out_size, void* d_ws, size_t ws_size,
                              hipStream_t stream) {
    const float* X   = (const float*)d_in[0];
    const float* Att = (const float*)d_in[1];
    const float* Wu  = (const float*)d_in[2];
    const float* bu  = (const float*)d_in[3];
    const float* Wr  = (const float*)d_in[4];
    const float* br  = (const float*)d_in[5];
    const float* Wh  = (const float*)d_in[6];
    const float* bh  = (const float*)d_in[7];
    float* out = (float*)d_out;

    gru_scan_kernel<<<dim3(2048 / BM), dim3(512), 0, stream>>>(
        X, Att, Wu, bu, Wr, br, Wh, bh, out);
}

// Round 6
// 452.873 us; speedup vs baseline: 1.5262x; 1.5262x over previous
//
#include <hip/hip_runtime.h>
#include <hip/hip_bf16.h>

// InterestEvolve: attention-modulated GRU scan. B=2048, T=200, D=128, U=128.
//
// R14 = R8 (the proven 254us/dispatch structure, CH=12) + async-issue staging:
//  - Next-chunk X/Att global loads are ISSUED at the top of each chunk into
//    registers (12 float4 + 1 float per thread) and PUBLISHED (pack+LDS write)
//    at the chunk boundary. ~12 steps between issue and use hide the HBM
//    latency that R8 exposed once per chunk (17 exposed bursts removed).
//  - In-loop barriers are lgkm-only (s_waitcnt lgkmcnt(0) + s_barrier,
//    sched_barrier(0)-hardened both sides; pattern validated in R10/R13) so
//    the in-flight prefetch loads are NOT drained 400 times. Chunk-boundary
//    barrier remains __syncthreads.
//  - launch_bounds(512,1): raises VGPR cap 128->256 for the held prefetch
//    regs. Free: grid=128 on 256 CUs -> 1 block/CU regardless.
//  - R13 post-mortem: its 489us came from weight-array SPILL (192-VGPR
//    weights under a 128 cap: WRITE_SIZE 1.8->22MB). Wide-consumer designs
//    are dead; 8 waves x 16 gatecols (96 VGPR weights) is the structure.
// Everything else identical to R8: K-major padded LDS (KCS=136), bias
// preloaded into MFMA C, v_cvt_pk packing, 2+2 split chains, within-chunk
// x-part pipelining. 128 blocks x 512 threads (8 waves, 2/SIMD).

#define T_LEN 200
#define D_DIM 128
#define U_DIM 128
#define BM    16
#define CH    12
#define NCH   ((T_LEN + CH - 1) / CH)   // 17, last chunk L=8
#define KCS   136          // ushorts per kchunk slot-row: 16 batch*8 + 8 pad
#define XSTEP (16 * KCS)   // ushorts per staged step (2176)

typedef __attribute__((ext_vector_type(8))) short bf16x8;
typedef __attribute__((ext_vector_type(4))) float f32x4;
typedef __attribute__((ext_vector_type(4))) unsigned int uint4v;

#define MFMA __builtin_amdgcn_mfma_f32_16x16x32_bf16

static __device__ __forceinline__ unsigned short f2bf(float f) {
    unsigned int u = __builtin_bit_cast(unsigned int, f);
    u += 0x7fffu + ((u >> 16) & 1u);       // round-to-nearest-even
    return (unsigned short)(u >> 16);
}
static __device__ __forceinline__ unsigned int pkbf2(float a, float b) {
    float2 t; t.x = a; t.y = b;
    __hip_bfloat162 v = __float22bfloat162_rn(t);   // v_cvt_pk_bf16_f32
    unsigned int u; __builtin_memcpy(&u, &v, 4);
    return u;
}
static __device__ __forceinline__ uint4v pack8u(float4 lo, float4 hi) {
    uint4v v;
    v[0] = pkbf2(lo.x, lo.y); v[1] = pkbf2(lo.z, lo.w);
    v[2] = pkbf2(hi.x, hi.y); v[3] = pkbf2(hi.z, hi.w);
    return v;
}
static __device__ __forceinline__ float fast_exp2(float x) {
#if __has_builtin(__builtin_amdgcn_exp2f)
    return __builtin_amdgcn_exp2f(x);
#else
    return exp2f(x);
#endif
}
static __device__ __forceinline__ float fast_rcp(float x) {
#if __has_builtin(__builtin_amdgcn_rcpf)
    return __builtin_amdgcn_rcpf(x);
#else
    return 1.0f / x;
#endif
}
// Barrier waiting ONLY on LDS ops; prefetch global loads stay in flight.
// sched_barrier(0) on both sides pins ds ops across it (rule #18).
static __device__ __forceinline__ void block_sync_lds() {
    asm volatile("s_waitcnt lgkmcnt(0)" ::: "memory");
    __builtin_amdgcn_sched_barrier(0);
    __builtin_amdgcn_s_barrier();
    __builtin_amdgcn_sched_barrier(0);
}

__global__ __launch_bounds__(512, 1)
void gru_scan_kernel(const float* __restrict__ X,    // (B,T,D)
                     const float* __restrict__ Att,  // (B,T,1)
                     const float* __restrict__ Wu, const float* __restrict__ bu,
                     const float* __restrict__ Wr, const float* __restrict__ br,
                     const float* __restrict__ Wh, const float* __restrict__ bh,
                     float* __restrict__ out)        // (B,U)
{
    __shared__ __align__(16) unsigned short x_sm[CH * XSTEP];  // 52224 B
    __shared__ __align__(16) unsigned short h_bf[XSTEP];       // 4352 B
    __shared__ __align__(16) unsigned short rh_bf[XSTEP];      // 4352 B
    __shared__ float a_sm[CH * BM];                            // 768 B

    const int tid  = threadIdx.x;
    const int wave = tid >> 6;    // owns gatecols [16*wave, 16*wave+16)
    const int lane = tid & 63;
    const int q    = lane >> 4;
    const int ln   = lane & 15;
    const int b0   = blockIdx.x * BM;

    const float INVLN2 = 1.4426950408889634f;

    // ---- Weight A-fragments (16 gatecols per wave), bf16, ln2-prescaled.
    // lane holds gatecol m = ln (tile base 16*wave), k = 32*kt + 8*q + j.
    // GEMM1 k: [h|x] rows of Wu/Wr. GEMM2 k: [x | r*h] rows of Wh.
    bf16x8 wu[8], wr[8], wh[8];
    f32x4 nbu, nbr, bh2;   // biases for gatecols 16w+4q+0..3 (C-operand preload)
    {
        const int tb = 16 * wave;
        const int c  = tb + ln;
        const f32x4 bu4 = *(const f32x4*)&bu[tb + 4 * q];
        const f32x4 br4 = *(const f32x4*)&br[tb + 4 * q];
        const f32x4 bh4 = *(const f32x4*)&bh[tb + 4 * q];
        #pragma unroll
        for (int r = 0; r < 4; ++r) {
            nbu[r] = -bu4[r] * INVLN2;
            nbr[r] = -br4[r] * INVLN2;
            bh2[r] = 2.0f * bh4[r] * INVLN2;
        }
        #pragma unroll
        for (int kt = 0; kt < 8; ++kt) {
            const int k0 = 32 * kt + 8 * q;
            bf16x8 vu, vr, vh;
            #pragma unroll
            for (int j = 0; j < 8; ++j) {
                vu[j] = (short)f2bf(Wu[(k0 + j) * U_DIM + c] * -INVLN2);
                vr[j] = (short)f2bf(Wr[(k0 + j) * U_DIM + c] * -INVLN2);
                vh[j] = (short)f2bf(Wh[(k0 + j) * U_DIM + c] * (2.0f * INVLN2));
            }
            wu[kt] = vu; wr[kt] = vr; wh[kt] = vh;
        }
    }

    float hreg[4] = {0.f, 0.f, 0.f, 0.f};   // fp32 h: batch=ln, gatecol=16w+4q+r

    // ---- clear ALL of h_bf / rh_bf (1088 uints each, incl. padding) ----
    {
        unsigned int* hz = (unsigned int*)h_bf;
        unsigned int* rz = (unsigned int*)rh_bf;
        for (int i = tid; i < XSTEP / 2; i += 512) { hz[i] = 0; rz[i] = 0; }
    }

    // staging map: thread = (s2 = tid>>8, srow = (tid>>4)&15, cs = tid&15)
    const int s2   = tid >> 8;
    const int srow = (tid >> 4) & 15;
    const int cs   = tid & 15;
    const float* xbase = X + (size_t)(b0 + srow) * T_LEN * D_DIM + cs * 8;

    // ---- prologue: stage chunk 0 synchronously (R8 staging phase) ----
    {
        float4 p0[CH];
        #pragma unroll
        for (int w2 = 0; w2 < CH / 2; ++w2) {
            const int t = 2 * w2 + s2;                    // 0..11 < T_LEN
            const float* src = xbase + (size_t)t * D_DIM;
            p0[2 * w2]     = *(const float4*)(src);
            p0[2 * w2 + 1] = *(const float4*)(src + 4);
        }
        float a_px = 0.0f;
        if (tid < BM * CH)
            a_px = Att[(size_t)(b0 + (tid & 15)) * T_LEN + (tid >> 4)];
        #pragma unroll
        for (int w2 = 0; w2 < CH / 2; ++w2) {
            const int s = 2 * w2 + s2;
            *(uint4v*)&x_sm[s * XSTEP + cs * KCS + srow * 8] =
                pack8u(p0[2 * w2], p0[2 * w2 + 1]);
        }
        if (tid < BM * CH) a_sm[tid] = a_px;
    }
    __syncthreads();

    int t0 = 0;
    for (int ch = 0; ch < NCH; ++ch) {
        const int L  = (t0 + CH <= T_LEN) ? CH : (T_LEN - t0);
        const bool st = (ch + 1 < NCH);

        // ---- ISSUE next-chunk loads now (published at chunk boundary).
        // ~12 steps of scan hide the HBM latency; lgkm-only barriers below
        // keep these in flight.
        float4 px[CH];
        float av = 0.0f;
        if (st) {
            const int tn0 = t0 + CH;
            #pragma unroll
            for (int w2 = 0; w2 < CH / 2; ++w2) {
                int t = tn0 + 2 * w2 + s2;
                t = (t < T_LEN) ? t : (T_LEN - 1);        // clamped, branchless
                const float* src = xbase + (size_t)t * D_DIM;
                px[2 * w2]     = *(const float4*)(src);
                px[2 * w2 + 1] = *(const float4*)(src + 4);
            }
            if (tid < BM * CH) {
                int ta = tn0 + (tid >> 4);
                ta = (ta < T_LEN) ? ta : (T_LEN - 1);
                av = Att[(size_t)(b0 + (tid & 15)) * T_LEN + ta];
            }
        }

        // ---- x-part accumulators for step 0 (bias preloaded into C) ----
        f32x4 acc_r, acc_u, acc_h;
        {
            bf16x8 xf[4];
            #pragma unroll
            for (int kt = 0; kt < 4; ++kt)
                xf[kt] = *(const bf16x8*)&x_sm[(4 * kt + q) * KCS + ln * 8];
            acc_r = nbr; acc_u = nbu; acc_h = bh2;
            #pragma unroll
            for (int kt = 0; kt < 4; ++kt) {
                acc_r = MFMA(wr[kt + 4], xf[kt], acc_r, 0, 0, 0);
                acc_u = MFMA(wu[kt + 4], xf[kt], acc_u, 0, 0, 0);
                acc_h = MFMA(wh[kt],     xf[kt], acc_h, 0, 0, 0);
            }
        }

        for (int s = 0; s < L; ++s) {
            // ---------- region 1: h-parts (r critical, 2+2 split) ----------
            bf16x8 hf[4];
            #pragma unroll
            for (int kt = 0; kt < 4; ++kt)
                hf[kt] = *(const bf16x8*)&h_bf[(4 * kt + q) * KCS + ln * 8];
            const float a_att = a_sm[s * BM + ln];

            f32x4 ra = acc_r, rb = (f32x4)0.0f;
            ra = MFMA(wr[0], hf[0], ra, 0, 0, 0);
            rb = MFMA(wr[2], hf[2], rb, 0, 0, 0);
            ra = MFMA(wr[1], hf[1], ra, 0, 0, 0);
            rb = MFMA(wr[3], hf[3], rb, 0, 0, 0);
            #pragma unroll
            for (int kt = 0; kt < 4; ++kt)
                acc_u = MFMA(wu[kt], hf[kt], acc_u, 0, 0, 0);

            {   // r sigmoid; r*h -> LDS (one ds_write_b64)
                float rh[4];
                #pragma unroll
                for (int r = 0; r < 4; ++r) {
                    float zr = ra[r] + rb[r];                   // = -z_r/ln2
                    float rv = fast_rcp(1.0f + fast_exp2(zr));  // sigmoid
                    rh[r] = rv * hreg[r];
                }
                uint2 wv; wv.x = pkbf2(rh[0], rh[1]); wv.y = pkbf2(rh[2], rh[3]);
                const int c8 = 2 * wave + (q >> 1);
                *(uint2*)&rh_bf[c8 * KCS + ln * 8 + (q & 1) * 4] = wv;
            }
            block_sync_lds();   // rh handoff (prefetch loads stay in flight)

            // ---------- region 2 ----------
            bf16x8 rf[4];
            #pragma unroll
            for (int kt = 0; kt < 4; ++kt)
                rf[kt] = *(const bf16x8*)&rh_bf[(4 * kt + q) * KCS + ln * 8];

            // u gate (off critical path)
            float uq[4];
            #pragma unroll
            for (int r = 0; r < 4; ++r) {
                float u = fast_rcp(1.0f + fast_exp2(acc_u[r]));  // sigmoid (-z/ln2)
                uq[r] = u * a_att;
            }

            // candidate: rh-part (critical, 2+2 split)
            f32x4 ha = acc_h, hb = (f32x4)0.0f;
            ha = MFMA(wh[4], rf[0], ha, 0, 0, 0);
            hb = MFMA(wh[6], rf[2], hb, 0, 0, 0);
            ha = MFMA(wh[5], rf[1], ha, 0, 0, 0);
            hb = MFMA(wh[7], rf[3], hb, 0, 0, 0);

            // tanh, h update, publish h
            #pragma unroll
            for (int r = 0; r < 4; ++r) {
                float z  = ha[r] + hb[r];                               // = 2*z_h/ln2
                float hh = 1.0f - 2.0f * fast_rcp(1.0f + fast_exp2(z)); // tanh
                float ho = hreg[r];
                hreg[r] = ho + uq[r] * (hh - ho);                       // u*hh+(1-u)*h
            }
            {
                uint2 wv; wv.x = pkbf2(hreg[0], hreg[1]); wv.y = pkbf2(hreg[2], hreg[3]);
                const int c8 = 2 * wave + (q >> 1);
                *(uint2*)&h_bf[c8 * KCS + ln * 8 + (q & 1) * 4] = wv;
            }

            // x-part accumulators for step s+1 (same chunk, off critical path)
            if (s + 1 < L) {
                bf16x8 xf[4];
                #pragma unroll
                for (int kt = 0; kt < 4; ++kt)
                    xf[kt] = *(const bf16x8*)&x_sm[(s + 1) * XSTEP + (4 * kt + q) * KCS + ln * 8];
                acc_r = nbr; acc_u = nbu; acc_h = bh2;
                #pragma unroll
                for (int kt = 0; kt < 4; ++kt) {
                    acc_r = MFMA(wr[kt + 4], xf[kt], acc_r, 0, 0, 0);
                    acc_u = MFMA(wu[kt + 4], xf[kt], acc_u, 0, 0, 0);
                    acc_h = MFMA(wh[kt],     xf[kt], acc_h, 0, 0, 0);
                }
            }
            block_sync_lds();   // h handoff
        }

        // ---- chunk boundary: publish prefetched chunk (loads landed long ago)
        if (st) {
            #pragma unroll
            for (int w2 = 0; w2 < CH / 2; ++w2) {
                const int s = 2 * w2 + s2;
                *(uint4v*)&x_sm[s * XSTEP + cs * KCS + srow * 8] =
                    pack8u(px[2 * w2], px[2 * w2 + 1]);
            }
            if (tid < BM * CH) a_sm[tid] = av;
            __syncthreads();
        }
        t0 += CH;
    }

    // ---- store h_final: 4 consecutive gatecols per thread -> dwordx4 ----
    {
        f32x4 v;
        #pragma unroll
        for (int r = 0; r < 4; ++r) v[r] = hreg[r];
        *(f32x4*)&out[(size_t)(b0 + ln) * U_DIM + 16 * wave + 4 * q] = v;
    }
}

extern "C" void kernel_launch(void* const* d_in, const int* in_sizes, int n_in,
                              void* d_out, int out_size, void* d_ws, size_t ws_size,
                              hipStream_t stream) {
    const float* X   = (const float*)d_in[0];
    const float* Att = (const float*)d_in[1];
    const float* Wu  = (const float*)d_in[2];
    const float* bu  = (const float*)d_in[3];
    const float* Wr  = (const float*)d_in[4];
    const float* br  = (const float*)d_in[5];
    const float* Wh  = (const float*)d_in[6];
    const float* bh  = (const float*)d_in[7];
    float* out = (float*)d_out;

    gru_scan_kernel<<<dim3(2048 / BM), dim3(512), 0, stream>>>(
        X, Att, Wu, bu, Wr, br, Wh, bh, out);
}